// Round 8
// baseline (190.523 us; speedup 1.0000x reference)
//
#include <hip/hip_runtime.h>
#include <math.h>

#define NPTS      128
#define DIM       512
#define NPAIR     8128
#define NTRI      341376
#define ROW_PAIR0 128
#define ROW_TRI0  8256     // 128 + 8128  (= 43 * 192, block-aligned!)
#define NROWS     349632   // 128 + 8128 + 341376 (= 1821 * 192, exact)
#define TILE      192
#define FILL_BLOCKS 1821   // exact: no bounds checks anywhere

// Kernel A: pairwise distances. One wave per (i, 64-wide j-slab).
// f64 accumulation (4 chains) -> essentially exact d for the d<=32 boundary.
__global__ __launch_bounds__(64) void vr_dist_kernel(
    const float* __restrict__ W,
    float* __restrict__ sigval,
    unsigned long long* __restrict__ adj) {
    __shared__ float wi[DIM];
    const int i    = blockIdx.x >> 1;
    const int half = blockIdx.x & 1;
    const int lane = threadIdx.x;
    const int j    = (half << 6) + lane;
    for (int c = lane; c < DIM; c += 64) wi[c] = W[i * DIM + c];
    __syncthreads();

    const float4* wj4 = (const float4*)(W + (size_t)j * DIM);
    const float4* wi4 = (const float4*)wi;
    double a0 = 0.0, a1 = 0.0, a2 = 0.0, a3 = 0.0;
    #pragma unroll 4
    for (int c = 0; c < DIM / 4; ++c) {
        float4 a = wi4[c];
        float4 b = wj4[c];
        double d0 = (double)a.x - (double)b.x;
        double d1 = (double)a.y - (double)b.y;
        double d2 = (double)a.z - (double)b.z;
        double d3 = (double)a.w - (double)b.w;
        a0 = fma(d0, d0, a0);
        a1 = fma(d1, d1, a1);
        a2 = fma(d2, d2, a2);
        a3 = fma(d3, d3, a3);
    }
    double dist = sqrt((a0 + a1) + (a2 + a3));

    unsigned long long m = __ballot(dist <= 32.0);
    if (lane == 0) adj[i * 2 + half] = m;

    if (j > i) {
        int p = 127 * i - ((i * (i - 1)) >> 1) + (j - i - 1);
        float x = 10.0f * (32.0f - (float)dist);
        sigval[p] = 1.0f / (1.0f + expf(-x));
    }
}

// Kernel B: zero-then-scatter fill of the 349632 x 128 output.
// Phase A: threads 0..191 decode their row (pure VALU) and ISSUE the needed
//          adj/sigval loads (drained by the barrier below).
// Phase B: all 256 threads stream constant-zero dwordx4 over the block's
//          96 KB slab — no data dependencies, rocclr-fill instruction pattern.
// Phase C: after one __syncthreads (orders zeros before overwrites), each
//          thread dword-stores its <=3 nonzeros into the L2-hot slab.
// Wave uniformity: segment boundaries 128 (wave-aligned) and 8256 (= 43
// blocks) mean every wave is single-kind -> no divergence.
__global__ __launch_bounds__(256) void vr_fill_kernel(
    const float* __restrict__ sigval,
    const unsigned long long* __restrict__ adj,
    float* __restrict__ out) {
    const int tid  = threadIdx.x;
    const int row0 = blockIdx.x * TILE;
    const int row  = row0 + tid;

    // ---- Phase A: decode one row per thread (threads 0..TILE-1) ----
    int kind = 0;                  // 0=idle, 1=identity, 2=pair, 3=triple
    int a = 0, b = 0, c = 0;
    unsigned long long wab = 0, wbc = 0, wac = 0;
    float sv = 0.0f;

    if (tid < TILE) {
        if (row < ROW_PAIR0) {
            kind = 1; a = row;
        } else if (row < ROW_TRI0) {
            kind = 2;
            int p = row - ROW_PAIR0;
            int lo = 0, hi = 127;
            #pragma unroll
            for (int it = 0; it < 7; ++it) {
                int m = (lo + hi + 1) >> 1;
                int C = 127 * m - ((m * (m - 1)) >> 1);
                if (C <= p) lo = m; else hi = m - 1;
            }
            a = lo;
            b = a + 1 + (p - (127 * a - ((a * (a - 1)) >> 1)));
            sv = sigval[p];                       // load in flight
        } else {
            kind = 3;
            int t = row - ROW_TRI0;
            int lo = 0, hi = 125;
            #pragma unroll
            for (int it = 0; it < 7; ++it) {
                int m = (lo + hi + 1) >> 1;
                int rem = NPTS - m;
                int T = NTRI - rem * (rem - 1) * (rem - 2) / 6;
                if (T <= t) lo = m; else hi = m - 1;
            }
            a = lo;
            int rema = NPTS - a;
            int r = t - (NTRI - rema * (rema - 1) * (rema - 2) / 6);
            lo = a + 1; hi = 126;
            #pragma unroll
            for (int it = 0; it < 7; ++it) {
                int m = (lo + hi + 1) >> 1;
                int C2 = ((m - a - 1) * (254 - a - m)) >> 1;
                if (C2 <= r) lo = m; else hi = m - 1;
            }
            b = lo;
            c = b + 1 + (r - (((b - a - 1) * (254 - a - b)) >> 1));
            wab = adj[(a << 1) + (b >> 6)];       // loads in flight
            wbc = adj[(b << 1) + (c >> 6)];
            wac = adj[(a << 1) + (c >> 6)];
        }
    }

    // ---- Phase B: stream zeros over this block's 96 KB slab ----
    const float4 z = make_float4(0.0f, 0.0f, 0.0f, 0.0f);
    float4* slab = (float4*)out + (size_t)blockIdx.x * (TILE * 32);
    #pragma unroll
    for (int k = 0; k < (TILE * 32) / 256; ++k)   // 24 dwordx4 per thread
        slab[k * 256 + tid] = z;

    __syncthreads();   // drains zero stores (and phase-A loads), then barrier

    // ---- Phase C: scatter the <=3 nonzeros per row (L2-hot lines) ----
    float* rp = out + (size_t)row * NPTS;
    if (kind == 1) {
        rp[a] = 1.0f;
    } else if (kind == 2) {
        rp[a] = sv;
        rp[b] = sv;
    } else if (kind == 3) {
        unsigned long long ok = (wab >> (b & 63)) & (wbc >> (c & 63)) &
                                (wac >> (c & 63)) & 1ull;
        if (ok) {
            rp[a] = 1.0f;
            rp[b] = 1.0f;
            rp[c] = 1.0f;
        }
    }
}

extern "C" void kernel_launch(void* const* d_in, const int* in_sizes, int n_in,
                              void* d_out, int out_size, void* d_ws, size_t ws_size,
                              hipStream_t stream) {
    const float* W = (const float*)d_in[0];
    float* out = (float*)d_out;

    // workspace layout: adj (256 u64 = 2048 B) | sigval (8128 f32)
    unsigned long long* adj = (unsigned long long*)d_ws;
    float* sigval = (float*)((char*)d_ws + 2048);

    vr_dist_kernel<<<256, 64, 0, stream>>>(W, sigval, adj);
    vr_fill_kernel<<<FILL_BLOCKS, 256, 0, stream>>>(sigval, adj, out);
}

// Round 9
// 187.069 us; speedup vs baseline: 1.0185x; 1.0185x over previous
//
#include <hip/hip_runtime.h>
#include <math.h>

#define NPTS      128
#define DIM       512
#define NPAIR     8128
#define NTRI      341376
#define ROW_PAIR0 128
#define ROW_TRI0  8256     // 128 + 8128
#define NROWS     349632   // 128 + 8128 + 341376
#define FILL_BLOCKS 1366   // ceil(NROWS / 256)

// Kernel A: pairwise distances. One wave per (i, 64-wide j-slab).
// f64 accumulation (4 chains) -> essentially exact d for the d<=32 boundary.
__global__ __launch_bounds__(64) void vr_dist_kernel(
    const float* __restrict__ W,
    float* __restrict__ sigval,
    unsigned long long* __restrict__ adj) {
    __shared__ float wi[DIM];
    const int i    = blockIdx.x >> 1;
    const int half = blockIdx.x & 1;
    const int lane = threadIdx.x;
    const int j    = (half << 6) + lane;
    for (int c = lane; c < DIM; c += 64) wi[c] = W[i * DIM + c];
    __syncthreads();

    const float4* wj4 = (const float4*)(W + (size_t)j * DIM);
    const float4* wi4 = (const float4*)wi;
    double a0 = 0.0, a1 = 0.0, a2 = 0.0, a3 = 0.0;
    #pragma unroll 4
    for (int c = 0; c < DIM / 4; ++c) {
        float4 a = wi4[c];
        float4 b = wj4[c];
        double d0 = (double)a.x - (double)b.x;
        double d1 = (double)a.y - (double)b.y;
        double d2 = (double)a.z - (double)b.z;
        double d3 = (double)a.w - (double)b.w;
        a0 = fma(d0, d0, a0);
        a1 = fma(d1, d1, a1);
        a2 = fma(d2, d2, a2);
        a3 = fma(d3, d3, a3);
    }
    double dist = sqrt((a0 + a1) + (a2 + a3));

    unsigned long long m = __ballot(dist <= 32.0);
    if (lane == 0) adj[i * 2 + half] = m;

    if (j > i) {
        int p = 127 * i - ((i * (i - 1)) >> 1) + (j - i - 1);
        float x = 10.0f * (32.0f - (float)dist);
        sigval[p] = 1.0f / (1.0f + expf(-x));
    }
}

// Kernel B (best variant, R6): fill 349632 x 128 output.
// Phase 1: thread t decodes row row0+t once -> LDS {128-bit col mask, val}.
// Phase 2: each wave owns a contiguous 32 KB slab (64 rows). Two halves of
//          16 iterations: stage all 32 LDS words into registers, then fire
//          16 back-to-back dwordx4 stores with no interleaved dependencies.
// Every byte written exactly once (no RMW, no second pass).
__global__ __launch_bounds__(256) void vr_fill_kernel(
    const float* __restrict__ sigval,
    const unsigned long long* __restrict__ adj,
    float4* __restrict__ out) {
    __shared__ unsigned long long sadj[256];
    __shared__ unsigned int smask[256][4];
    __shared__ float sval[256];

    const int tid = threadIdx.x;
    sadj[tid] = adj[tid];
    __syncthreads();

    const int row0 = blockIdx.x * 256;
    const int row  = row0 + tid;

    // ---- Phase 1: decode one row per thread ----
    int a = 255, b = 255, c = 255;      // sentinels: (x>>5)==7 never matches
    float val = 0.0f;
    if (row < ROW_PAIR0) {
        a = row; val = 1.0f;
    } else if (row < ROW_TRI0) {
        int p = row - ROW_PAIR0;
        int lo = 0, hi = 127;
        #pragma unroll
        for (int it = 0; it < 7; ++it) {
            int m = (lo + hi + 1) >> 1;
            int C = 127 * m - ((m * (m - 1)) >> 1);
            if (C <= p) lo = m; else hi = m - 1;
        }
        a = lo;
        b = a + 1 + (p - (127 * a - ((a * (a - 1)) >> 1)));
        val = sigval[p];
    } else if (row < NROWS) {
        int t = row - ROW_TRI0;
        int lo = 0, hi = 125;
        #pragma unroll
        for (int it = 0; it < 7; ++it) {
            int m = (lo + hi + 1) >> 1;
            int rem = NPTS - m;
            int T = NTRI - rem * (rem - 1) * (rem - 2) / 6;
            if (T <= t) lo = m; else hi = m - 1;
        }
        a = lo;
        int rema = NPTS - a;
        int r = t - (NTRI - rema * (rema - 1) * (rema - 2) / 6);
        lo = a + 1; hi = 126;
        #pragma unroll
        for (int it = 0; it < 7; ++it) {
            int m = (lo + hi + 1) >> 1;
            int C2 = ((m - a - 1) * (254 - a - m)) >> 1;
            if (C2 <= r) lo = m; else hi = m - 1;
        }
        b = lo;
        c = b + 1 + (r - (((b - a - 1) * (254 - a - b)) >> 1));

        unsigned long long bab = sadj[(a << 1) + (b >> 6)] >> (b & 63);
        unsigned long long bbc = sadj[(b << 1) + (c >> 6)] >> (c & 63);
        unsigned long long bac = sadj[(a << 1) + (c >> 6)] >> (c & 63);
        val = (float)(bab & bbc & bac & 1ull);
    }
    #pragma unroll
    for (int w = 0; w < 4; ++w) {
        unsigned int mw = 0;
        mw |= ((a >> 5) == w) ? (1u << (a & 31)) : 0u;
        mw |= ((b >> 5) == w) ? (1u << (b & 31)) : 0u;
        mw |= ((c >> 5) == w) ? (1u << (c & 31)) : 0u;
        smask[tid][w] = mw;
    }
    sval[tid] = val;
    __syncthreads();

    // ---- Phase 2: wave-contiguous staged store sweeps ----
    const int lane  = tid & 63;
    const int wv    = tid >> 6;          // wave id 0..3
    const int col4  = lane & 31;         // float4 index within a row
    const int rhalf = lane >> 5;         // 0..1 (two rows per wave-store)
    const int widx  = col4 >> 3;         // mask word
    const int sh    = (col4 & 7) << 2;   // nibble shift
    const int rbase = wv << 6;           // this wave's local row base (64 rows)

    // iteration kk writes rows rbase + 2*kk + rhalf; wave covers 32 KB contig.
    float4* p = out + ((size_t)(row0 + rbase + rhalf) << 5) + col4;

    #pragma unroll
    for (int h = 0; h < 2; ++h) {
        unsigned int nib[16];
        float        vv[16];
        #pragma unroll
        for (int k = 0; k < 16; ++k) {
            int rl = rbase + (((h << 4) + k) << 1) + rhalf;
            nib[k] = smask[rl][widx] >> sh;
            vv[k]  = sval[rl];
        }
        #pragma unroll
        for (int k = 0; k < 16; ++k) {
            int kk = (h << 4) + k;
            float4 v;
            v.x = (nib[k] & 1u) ? vv[k] : 0.0f;
            v.y = (nib[k] & 2u) ? vv[k] : 0.0f;
            v.z = (nib[k] & 4u) ? vv[k] : 0.0f;
            v.w = (nib[k] & 8u) ? vv[k] : 0.0f;
            int grow = row0 + rbase + (kk << 1) + rhalf;
            if (grow < NROWS) p[(size_t)kk << 6] = v;
        }
    }
}

extern "C" void kernel_launch(void* const* d_in, const int* in_sizes, int n_in,
                              void* d_out, int out_size, void* d_ws, size_t ws_size,
                              hipStream_t stream) {
    const float* W = (const float*)d_in[0];
    float* out = (float*)d_out;

    // workspace layout: adj (256 u64 = 2048 B) | sigval (8128 f32)
    unsigned long long* adj = (unsigned long long*)d_ws;
    float* sigval = (float*)((char*)d_ws + 2048);

    vr_dist_kernel<<<256, 64, 0, stream>>>(W, sigval, adj);
    vr_fill_kernel<<<FILL_BLOCKS, 256, 0, stream>>>(sigval, adj, (float4*)out);
}